// Round 8
// baseline (465.135 us; speedup 1.0000x reference)
//
#include <hip/hip_runtime.h>
#include <hip/hip_bf16.h>

// Problem constants (from reference)
constexpr int NN   = 10000;  // N_NODES
constexpr int DMAX = 128;    // D_MAX
constexpr int ROWS = 128;    // B*F = 2*64 values per node

// ---------------------------------------------------------------------------
// Kernel 1: transpose x (128, 10000) -> xT (10000, 128): each node's 128
// (b,f) values become one contiguous 512B line (coalesced neighbor gathers).
// ---------------------------------------------------------------------------
__global__ __launch_bounds__(256) void transpose_kernel(
    const float* __restrict__ x, float* __restrict__ xT)
{
    __shared__ float tile[32][33];
    const int n0 = blockIdx.x * 32;
    const int r0 = blockIdx.y * 32;
    const int tx = threadIdx.x;   // 0..31
    const int ty = threadIdx.y;   // 0..7
    #pragma unroll
    for (int i = 0; i < 32; i += 8) {
        const int r = r0 + ty + i;
        const int n = n0 + tx;
        if (n < NN) tile[ty + i][tx] = x[(size_t)r * NN + n];
    }
    __syncthreads();
    #pragma unroll
    for (int i = 0; i < 32; i += 8) {
        const int n = n0 + ty + i;
        const int r = r0 + tx;
        if (n < NN) xT[(size_t)n * ROWS + r] = tile[tx][ty + i];
    }
}

// ---------------------------------------------------------------------------
// Register-resident exact median, 4 lanes per column (q = lane>>4), each lane
// holds up to QC<=32 values in VGPRs (gathered once, 32-bit addressing).
// Bracketed quickselect, same proven termination logic as rounds 2-6:
//   pass: c = #{v<=m}; snap passes also track mx=max{v<=m}, mn=min{v>m}.
//   c==mid+1 -> x=mx ; c==mid -> x=mn ; lo>=hi -> x=lo  (duplicate-safe)
//   c>mid+1 -> hi=mx|m ; c<mid -> lo=mn|m  (bracket shrinks strictly)
// dosnap is WAVE-UNIFORM (ballot) -> only one loop body issues per pass;
// pivot = secant on the empirical CDF with bracket clamps.
// The 4 lanes of a column carry identical scalar state -> lockstep exit.
//
// Round-7 note: rounds 5/6 spilled (343-623 MB scratch WRITE_SIZE) because
// the allocator pinned itself to the 64-VGPR occupancy tier under
// __launch_bounds__(256,4). Kernel now declares (256,2) -> VGPR cap 256,
// letting the ~90 genuinely-live regs stay in the register file.
// ---------------------------------------------------------------------------
template<int QC>
__device__ __forceinline__ float median_sel(const float* __restrict__ xT,
                                            const int* __restrict__ idxp,
                                            int ln, int col, int q)
{
    const float INF = 1e30f;
    float data[QC];
    #pragma unroll
    for (int j = 0; j < QC; ++j) {
        const int  jj    = q * QC + j;
        const bool valid = jj < ln;
        const int  nb    = valid ? idxp[jj] : 0;     // idxp has DMAX entries
        const float v    = xT[(nb << 7) + col];      // always in-bounds
        data[j] = valid ? v : INF;                   // pads never count
    }

    const int   mid  = (ln - 1) >> 1;
    const float midf = (float)mid + 0.5f;
    const float invs = 1.0f / (0.4f * (float)ln);    // Newton slope (N(0,1) pdf)
    float lo = -64.f, hi = 64.f, m = 0.f, x = 0.f;   // |data| < 10 << 64
    float mp = 0.f, cpf = 0.f;
    bool active = true, need_snap = false, have_prev = false;
    int  pass = 0;

    while (__ballot(active) != 0ull) {
        const bool dosnap = (pass >= 3) || (__ballot(need_snap) != 0ull); // uniform

        int   cA = 0, cB = 0;
        float mx0 = -INF, mx1 = -INF, mn0 = INF, mn1 = INF;
        if (dosnap) {
            #pragma unroll
            for (int j = 0; j < QC; j += 2) {
                const float v0 = data[j], v1 = data[j + 1];
                const bool  l0 = v0 <= m, l1 = v1 <= m;
                cA += l0; cB += l1;
                mx0 = l0 ? fmaxf(mx0, v0) : mx0;  mn0 = l0 ? mn0 : fminf(mn0, v0);
                mx1 = l1 ? fmaxf(mx1, v1) : mx1;  mn1 = l1 ? mn1 : fminf(mn1, v1);
            }
        } else {
            #pragma unroll
            for (int j = 0; j < QC; j += 2) {
                cA += data[j] <= m;  cB += data[j + 1] <= m;
            }
        }
        int c = cA + cB;
        c += __shfl_xor(c, 16);                      // combine the 4 quarters
        c += __shfl_xor(c, 32);
        float mx = fmaxf(mx0, mx1), mn = fminf(mn0, mn1);
        if (dosnap) {
            mx = fmaxf(mx, __shfl_xor(mx, 16));
            mx = fmaxf(mx, __shfl_xor(mx, 32));
            mn = fminf(mn, __shfl_xor(mn, 16));
            mn = fminf(mn, __shfl_xor(mn, 32));
        }

        if (active) {
            const float fc = (float)c;
            if (dosnap) {
                need_snap = false;
                if      (c == mid + 1) { x = mx; active = false; }
                else if (c == mid)     { x = mn; active = false; }
                else {
                    if (c > mid + 1) hi = mx; else lo = mn;     // snap: strict shrink
                    if (lo >= hi) { x = lo; active = false; }
                    else {
                        const float dd = fc - cpf;
                        float mN = (have_prev && dd != 0.f)
                                 ? m + (midf - fc) * (m - mp) * __builtin_amdgcn_rcpf(dd)
                                 : m + (midf - fc) * invs;
                        mp = m; cpf = fc; have_prev = true;
                        if (!(mN > lo && mN < hi)) mN = 0.5f * (lo + hi);
                        if (mN >= hi) mN = lo;                  // termination guard
                        m = mN;
                    }
                }
            } else {
                if (c == mid + 1 || c == mid) {
                    need_snap = true;                // redo same pivot with snap
                } else {
                    if (c > mid + 1) hi = m; else lo = m;
                    const float dd = fc - cpf;
                    float mN = (have_prev && dd != 0.f)
                             ? m + (midf - fc) * (m - mp) * __builtin_amdgcn_rcpf(dd)
                             : m + (midf - fc) * invs;
                    mp = m; cpf = fc; have_prev = true;
                    if (!(mN > lo && mN < hi)) mN = 0.5f * (lo + hi);
                    if (mN >= hi) mN = lo;
                    m = mN;
                }
            }
        }
        ++pass;
    }
    return x;
}

// ln is block-uniform -> this branch chain is uniform; only one path executes.
// Buckets step by 16 slots (4 lanes x 4) to keep padding waste <= 15 compares.
__device__ __forceinline__ float median_dispatch(const float* __restrict__ xT,
                                                 const int* __restrict__ idxp,
                                                 int ln, int col, int q)
{
    if (ln <= 16)  return median_sel< 4>(xT, idxp, ln, col, q);
    if (ln <= 32)  return median_sel< 8>(xT, idxp, ln, col, q);
    if (ln <= 48)  return median_sel<12>(xT, idxp, ln, col, q);
    if (ln <= 64)  return median_sel<16>(xT, idxp, ln, col, q);
    if (ln <= 80)  return median_sel<20>(xT, idxp, ln, col, q);
    if (ln <= 96)  return median_sel<24>(xT, idxp, ln, col, q);
    if (ln <= 112) return median_sel<28>(xT, idxp, ln, col, q);
    return median_sel<32>(xT, idxp, ln, col, q);
}

// ---------------------------------------------------------------------------
// Kernel 2: no LDS, no __syncthreads. Block = 256 thr = 4 independent waves;
// 2 blocks per node, each block owns 64 columns; each wave owns 16 columns;
// each column is selected by 4 lanes (quarters).
// __launch_bounds__(256, 2): VGPR cap 256 -> allocator must not spill at the
// 64-reg tier (round-5/6 lesson: (256,4) produced 343-623 MB scratch traffic).
// ---------------------------------------------------------------------------
__global__ __launch_bounds__(256, 2) void median_combine(
    const float* __restrict__ xT, const float* __restrict__ w,
    const int* __restrict__ nidx, const int* __restrict__ nlen,
    float* __restrict__ out)
{
    const int t   = threadIdx.x;
    const int wv  = t >> 6;            // wave 0..3
    const int l   = t & 63;
    const int g   = l & 15;            // column within wave's group
    const int q   = l >> 4;            // quarter 0..3
    const int n   = blockIdx.x >> 1;
    const int col = ((blockIdx.x & 1) << 6) | (wv << 4) | g;   // 0..127

    float medk[2];
    #pragma unroll
    for (int k = 0; k < 2; ++k) {
        const int ln = nlen[k * NN + n];                     // block-uniform
        const int* idxp = nidx + ((size_t)k * NN + n) * DMAX;
        medk[k] = median_dispatch(xT, idxp, ln, col, q);
    }

    if (q == 0) {
        const float xv = xT[(n << 7) + col];
        out[col * NN + n] = w[0] * xv + w[1] * medk[0] + w[2] * medk[1];
    }
}

extern "C" void kernel_launch(void* const* d_in, const int* in_sizes, int n_in,
                              void* d_out, int out_size, void* d_ws, size_t ws_size,
                              hipStream_t stream) {
    const float* x    = (const float*)d_in[0];   // (2,64,10000) f32
    const float* w    = (const float*)d_in[1];   // (1,3) f32
    const int*   nidx = (const int*)d_in[2];     // (2,10000,128) i32
    const int*   nlen = (const int*)d_in[3];     // (2,10000) i32
    float* out = (float*)d_out;                  // (2,64,10000) f32
    float* xT  = (float*)d_ws;                   // 10000*128 f32 = 5.12 MB scratch

    dim3 tb(32, 8);
    dim3 tg((NN + 31) / 32, ROWS / 32);
    transpose_kernel<<<tg, tb, 0, stream>>>(x, xT);
    median_combine<<<NN * 2, 256, 0, stream>>>(xT, w, nidx, nlen, out);
}

// Round 9
// 346.256 us; speedup vs baseline: 1.3433x; 1.3433x over previous
//
#include <hip/hip_runtime.h>
#include <hip/hip_bf16.h>

// Problem constants (from reference)
constexpr int NN   = 10000;  // N_NODES
constexpr int DMAX = 128;    // D_MAX
constexpr int ROWS = 128;    // B*F = 2*64 values per node

// ---------------------------------------------------------------------------
// Kernel 1: transpose x (128, 10000) -> xT (10000, 128): each node's 128
// (b,f) values become one contiguous 512B line (coalesced neighbor gathers).
// ---------------------------------------------------------------------------
__global__ __launch_bounds__(256) void transpose_kernel(
    const float* __restrict__ x, float* __restrict__ xT)
{
    __shared__ float tile[32][33];
    const int n0 = blockIdx.x * 32;
    const int r0 = blockIdx.y * 32;
    const int tx = threadIdx.x;   // 0..31
    const int ty = threadIdx.y;   // 0..7
    #pragma unroll
    for (int i = 0; i < 32; i += 8) {
        const int r = r0 + ty + i;
        const int n = n0 + tx;
        if (n < NN) tile[ty + i][tx] = x[(size_t)r * NN + n];
    }
    __syncthreads();
    #pragma unroll
    for (int i = 0; i < 32; i += 8) {
        const int n = n0 + ty + i;
        const int r = r0 + tx;
        if (n < NN) xT[(size_t)n * ROWS + r] = tile[tx][ty + i];
    }
}

// ---------------------------------------------------------------------------
// Streaming exact median, ONE lane per column. The lane re-streams its
// column's neighbor values from L2-resident xT on every quickselect pass:
//   nb = idxp[j] is wave-uniform (scalar load); lane address nb*128+col is
//   64 consecutive floats -> one coalesced 256B load per j for 64 columns.
// No data[] register cache (round 5/6/8 lesson: it either spills or caps
// occupancy), no LDS, no shfl (lane owns the whole column -> c/mx/mn are
// already complete). Bracketed quickselect with snap, termination logic
// proven in rounds 2-8:
//   pass: c = #{v<=m}; snap passes also track mx=max{v<=m}, mn=min{v>m}.
//   c==mid+1 -> x=mx ; c==mid -> x=mn ; lo>=hi -> x=lo  (duplicate-safe)
//   c>mid+1 -> hi=mx|m ; c<mid -> lo=mn|m  (bracket shrinks strictly)
// dosnap is wave-uniform (ballot) -> one loop body issues per pass; pivot =
// secant on the empirical CDF, clamped to the bracket (mN>=hi -> mN=lo
// termination guard). Snap from pass 1 on (lane-private c is exact, and
// pass-0 count narrows the bracket enough that pass 1 usually terminates).
// ---------------------------------------------------------------------------
__device__ __forceinline__ float stream_median(const float* __restrict__ xT,
                                               const int* __restrict__ idxp,
                                               int ln, int col)
{
    const float INF  = 1e30f;
    const int   mid  = (ln - 1) >> 1;
    const float midf = (float)mid + 0.5f;
    const float invs = 1.0f / (0.4f * (float)ln);   // Newton slope (N(0,1) pdf)
    float lo = -64.f, hi = 64.f, m = 0.f, x = 0.f;  // |data| < 10 << 64
    float mp = 0.f, cpf = 0.f;
    bool active = true, need_snap = false, have_prev = false;
    int  pass = 0;

    while (__ballot(active) != 0ull) {
        const bool dosnap = (pass >= 1) || (__ballot(need_snap) != 0ull); // uniform

        int   c  = 0;
        float mx = -INF, mn = INF;
        if (dosnap) {
            #pragma unroll 4
            for (int j = 0; j < ln; ++j) {          // uniform trip count
                const float v  = xT[(idxp[j] << 7) + col];
                const bool  le = v <= m;
                c  += le ? 1 : 0;
                mx  = le ? fmaxf(mx, v) : mx;
                mn  = le ? mn : fminf(mn, v);
            }
        } else {
            #pragma unroll 4
            for (int j = 0; j < ln; ++j)
                c += (xT[(idxp[j] << 7) + col] <= m) ? 1 : 0;
        }

        if (active) {
            const float fc = (float)c;
            if (dosnap) {
                need_snap = false;
                if      (c == mid + 1) { x = mx; active = false; }
                else if (c == mid)     { x = mn; active = false; }
                else {
                    if (c > mid + 1) hi = mx; else lo = mn;     // snap: strict shrink
                    if (lo >= hi) { x = lo; active = false; }
                    else {
                        const float dd = fc - cpf;
                        float mN = (have_prev && dd != 0.f)
                                 ? m + (midf - fc) * (m - mp) * __builtin_amdgcn_rcpf(dd)
                                 : m + (midf - fc) * invs;
                        mp = m; cpf = fc; have_prev = true;
                        if (!(mN > lo && mN < hi)) mN = 0.5f * (lo + hi);
                        if (mN >= hi) mN = lo;                  // termination guard
                        m = mN;
                    }
                }
            } else {
                if (c == mid + 1 || c == mid) {
                    need_snap = true;                // redo same pivot with snap
                } else {
                    if (c > mid + 1) hi = m; else lo = m;
                    const float dd = fc - cpf;
                    float mN = (have_prev && dd != 0.f)
                             ? m + (midf - fc) * (m - mp) * __builtin_amdgcn_rcpf(dd)
                             : m + (midf - fc) * invs;
                    mp = m; cpf = fc; have_prev = true;
                    if (!(mN > lo && mN < hi)) mN = 0.5f * (lo + hi);
                    if (mN >= hi) mN = lo;
                    m = mN;
                }
            }
        }
        ++pass;
    }
    return x;
}

// ---------------------------------------------------------------------------
// Kernel 2: one block (128 thr = 2 waves) per node; thread t owns column t
// end-to-end (both hops + combine + write). No LDS, no syncthreads, no shfl.
// __launch_bounds__(128, 8): 8 waves/SIMD tier -> VGPR cap 64 (state is ~40
// regs; there is no data[] array to spill).
// ---------------------------------------------------------------------------
__global__ __launch_bounds__(128, 8) void median_combine(
    const float* __restrict__ xT, const float* __restrict__ w,
    const int* __restrict__ nidx, const int* __restrict__ nlen,
    float* __restrict__ out)
{
    const int t = threadIdx.x;   // column 0..127  (= b*64+f)
    const int n = blockIdx.x;

    float medk[2];
    #pragma unroll
    for (int k = 0; k < 2; ++k) {
        const int ln = nlen[k * NN + n];                     // wave-uniform
        const int* idxp = nidx + ((size_t)k * NN + n) * DMAX;
        medk[k] = stream_median(xT, idxp, ln, t);
    }

    const float xv = xT[(n << 7) + t];
    out[t * NN + n] = w[0] * xv + w[1] * medk[0] + w[2] * medk[1];
}

extern "C" void kernel_launch(void* const* d_in, const int* in_sizes, int n_in,
                              void* d_out, int out_size, void* d_ws, size_t ws_size,
                              hipStream_t stream) {
    const float* x    = (const float*)d_in[0];   // (2,64,10000) f32
    const float* w    = (const float*)d_in[1];   // (1,3) f32
    const int*   nidx = (const int*)d_in[2];     // (2,10000,128) i32
    const int*   nlen = (const int*)d_in[3];     // (2,10000) i32
    float* out = (float*)d_out;                  // (2,64,10000) f32
    float* xT  = (float*)d_ws;                   // 10000*128 f32 = 5.12 MB scratch

    dim3 tb(32, 8);
    dim3 tg((NN + 31) / 32, ROWS / 32);
    transpose_kernel<<<tg, tb, 0, stream>>>(x, xT);
    median_combine<<<NN, 128, 0, stream>>>(xT, w, nidx, nlen, out);
}